// Round 5
// baseline (354.512 us; speedup 1.0000x reference)
//
#include <hip/hip_runtime.h>
#include <hip/hip_bf16.h>

typedef float        f32x4  __attribute__((ext_vector_type(4)));
typedef int          i32x4  __attribute__((ext_vector_type(4)));
typedef int          i32x16 __attribute__((ext_vector_type(16)));
typedef unsigned int u32x2  __attribute__((ext_vector_type(2)));
typedef unsigned long long u64x2 __attribute__((ext_vector_type(2)));

// ws layout
#define S1_OFF   0u
#define S1_BYTES (64u * 8192u * 32u)   // 16,777,216 B (bitpacked s1: [t][b][256 bits], bit p = h)
#define PART_OFF S1_BYTES

static __device__ __forceinline__ float clamp01(float v) {
    return fminf(fmaxf(v, 0.0f), 1.0f);
}

// ---------------------------------------------------------------------------
// k1: cur_in = x_t @ W_in^T + b_in (fp32), 64-step layer-1 recurrence,
// s1 bitpacked via __ballot.  8 batches/block, 1024 blocks.
// lane owns h = {lane,+64,+128,+192}; grp = tid>>6 owns batches {grp*2,+1}.
// t-loop uses r1(t) = s1(t-1): one compare per state per t, reset folded
// into a per-state selected bias (curb = s ? cur-thr : cur).
// ---------------------------------------------------------------------------
__global__ __launch_bounds__(256) void k1_layer1(
    const float* __restrict__ x, const float* __restrict__ W_in,
    const float* __restrict__ b_in, const float* __restrict__ beta_in,
    const float* __restrict__ thr_in, unsigned long long* __restrict__ S1) {
    __shared__ float Xs[8][256];
    int tid = threadIdx.x;
    int b0 = blockIdx.x * 8;
    #pragma unroll
    for (int i = 0; i < 8; ++i) {
        int idx = i * 256 + tid;
        int bb = idx >> 8, d = idx & 255;
        Xs[bb][d] = x[((size_t)(b0 + bb) * 256 + d) * 64];  // x[0,b,d,0]
    }
    __syncthreads();

    int lane = tid & 63, grp = tid >> 6;
    int   h[4]; float bi[4], b1[4], th[4];
    #pragma unroll
    for (int i = 0; i < 4; ++i) {
        h[i]  = i * 64 + lane;
        bi[i] = b_in[h[i]];
        b1[i] = clamp01(beta_in[h[i]]);
        th[i] = thr_in[h[i]];
    }
    float cur[4][2];
    #pragma unroll
    for (int i = 0; i < 4; ++i)
        #pragma unroll
        for (int bb = 0; bb < 2; ++bb) cur[i][bb] = bi[i];

    #pragma unroll 4
    for (int d4 = 0; d4 < 64; ++d4) {
        f32x4 w[4];
        #pragma unroll
        for (int i = 0; i < 4; ++i)
            w[i] = *(const f32x4*)(W_in + (size_t)h[i] * 256 + d4 * 4);
        #pragma unroll
        for (int bb = 0; bb < 2; ++bb) {
            f32x4 xv = *(const f32x4*)(&Xs[grp * 2 + bb][d4 * 4]);
            #pragma unroll
            for (int i = 0; i < 4; ++i)
                cur[i][bb] += w[i][0]*xv[0] + w[i][1]*xv[1] + w[i][2]*xv[2] + w[i][3]*xv[3];
        }
    }

    float m1[4][2], curm[4][2], curb[4][2];
    #pragma unroll
    for (int i = 0; i < 4; ++i)
        #pragma unroll
        for (int bb = 0; bb < 2; ++bb) {
            m1[i][bb]   = 0.0f;
            curm[i][bb] = cur[i][bb] - th[i];
            curb[i][bb] = cur[i][bb];        // r1(0) = spike(-thr) = 0
        }

    int li = lane & 3;
    #pragma unroll 1
    for (int t = 0; t < 64; ++t) {
        unsigned long long arr[8];
        #pragma unroll
        for (int i = 0; i < 4; ++i) {
            #pragma unroll
            for (int bb = 0; bb < 2; ++bb) {
                float mm = fmaf(b1[i], m1[i][bb], curb[i][bb]);
                m1[i][bb] = mm;
                bool s = mm > th[i];
                arr[bb * 4 + i] = __ballot(s);               // s1 bits, h = i*64+lane
                curb[i][bb] = s ? curm[i][bb] : cur[i][bb];  // next reset folded in
            }
        }
        unsigned long long e0 = (li & 2) ? ((li & 1) ? arr[6] : arr[4])
                                         : ((li & 1) ? arr[2] : arr[0]);
        unsigned long long e1 = (li & 2) ? ((li & 1) ? arr[7] : arr[5])
                                         : ((li & 1) ? arr[3] : arr[1]);
        if (lane < 4) {
            unsigned long long* p =
                S1 + ((size_t)t * 8192 + (size_t)(b0 + grp * 2)) * 4 + (size_t)li * 2;
            *(u64x2*)p = (u64x2){e0, e1};
        }
    }
}

// ---------------------------------------------------------------------------
// k2: fused 64-step loop with 32x32x16 i8 MFMA.
// 256 blocks x 512 thr (8 waves = 2/SIMD).  Block owns 32 batch rows; wave
// wid owns cols [wid*32,+32).  A-operand (spike bytes, shared by all waves)
// is unpacked ONCE per block per t into double-buffered XOR-swizzled LDS:
// wave w unpacks rows [w*4,+4), lane slice = 16 bits -> 16 bytes -> b128.
// B = 3 signed-i8 base-256 digits of W_h (built in prologue, 96 VGPRs).
// A/B k-index: H = (lane>>5)*128 + ks*8 + j (consistent on both sides, so
// any HW k-permutation cancels); C/D layout per m74 (col = lane&31).
// Epilogue: s = ((d0<<8)+d1)<<8)+d2 exact int; bias-folded reset; spike
// count -> G = b3*G + cnt per t; final acc3 = wo*G.
// ---------------------------------------------------------------------------
__global__ __launch_bounds__(512, 2) void k2_main(
    const unsigned int* __restrict__ S1,
    const float* __restrict__ W_h,
    const float* __restrict__ b_h, const float* __restrict__ beta_h,
    const float* __restrict__ thr_h, const float* __restrict__ W_o,
    const float* __restrict__ beta_o, float* __restrict__ partials) {
    __shared__ __align__(16) unsigned char AL[2][32][256];
    __shared__ float wred[8];
    int tid = threadIdx.x, lane = tid & 63, wid = tid >> 6;
    int l31 = lane & 31, half = lane >> 5;
    int hcol = wid * 32 + l31;

    // ---- prologue: B digit-fragments (3 sp x 16 ks longs = 96 VGPRs) ----
    long Bf[3][16];
    #pragma unroll
    for (int ks = 0; ks < 16; ++ks) {
        const float* wp = W_h + (size_t)hcol * 256 + half * 128 + ks * 8;
        unsigned int lo[3] = {0, 0, 0}, hi[3] = {0, 0, 0};
        #pragma unroll
        for (int j = 0; j < 8; ++j) {
            float w = wp[j];
            int v  = (int)rintf(w * 0x1p23f);
            int a2 = ((v + 128) & 255) - 128;  v = (v - a2) >> 8;
            int a1 = ((v + 128) & 255) - 128;  int a0 = (v - a1) >> 8;
            unsigned int sh = (j & 3) * 8;
            unsigned int* dst = (j < 4) ? lo : hi;
            dst[0] |= (unsigned int)(a0 & 255) << sh;
            dst[1] |= (unsigned int)(a1 & 255) << sh;
            dst[2] |= (unsigned int)(a2 & 255) << sh;
        }
        #pragma unroll
        for (int sp = 0; sp < 3; ++sp) {
            u32x2 pk = {lo[sp], hi[sp]};
            Bf[sp][ks] = __builtin_bit_cast(long, pk);
        }
    }

    float thr = thr_h[hcol];
    float b2  = clamp01(beta_h[hcol]);
    float wo  = W_o[hcol];
    float bh  = b_h[hcol];
    float bhm = bh - thr;
    float b3  = clamp01(beta_o[0]);

    float m2[16], bias[16];
    #pragma unroll
    for (int r = 0; r < 16; ++r) { m2[r] = 0.0f; bias[r] = bh; }
    float G = 0.0f;

    // ---- unpack-writer params (wave w unpacks rows w*4..+3) ----
    int urow  = wid * 4 + (lane >> 4);
    int uslot = lane & 15;                         // H-slice = uslot*16
    int ushift = (uslot & 1) * 16;
    const unsigned int* bitp =
        S1 + ((size_t)blockIdx.x * 32 + urow) * 8 + (uslot >> 1);
    unsigned char* wbase[2];
    unsigned char* rbase[2];
    #pragma unroll
    for (int nb = 0; nb < 2; ++nb) {
        wbase[nb] = &AL[nb][urow][0] + ((uslot * 16) ^ ((urow & 7) << 4));
        rbase[nb] = &AL[nb][l31][0];
    }

    auto SPREAD_WRITE = [&](unsigned int bword, int nb) {
        unsigned int v16 = (bword >> ushift) & 0xFFFFu;
        i32x4 sw;
        sw[0] = (int)((v16 & 0xFu)         * 0x204081u & 0x01010101u);
        sw[1] = (int)(((v16 >> 4) & 0xFu)  * 0x204081u & 0x01010101u);
        sw[2] = (int)(((v16 >> 8) & 0xFu)  * 0x204081u & 0x01010101u);
        sw[3] = (int)((v16 >> 12)          * 0x204081u & 0x01010101u);
        *(i32x4*)wbase[nb] = sw;
    };

    // prologue: stage t=0, prefetch t=1 bits
    SPREAD_WRITE(bitp[0], 0);
    unsigned int bnext = bitp[65536];
    __syncthreads();

    #pragma unroll 1
    for (int t = 0; t < 64; ++t) {
        int nb = t & 1;
        if (t < 63) SPREAD_WRITE(bnext, nb ^ 1);
        if (t < 62) bnext = bitp[(size_t)(t + 2) * 65536];

        i32x16 acc0 = {0,0,0,0,0,0,0,0,0,0,0,0,0,0,0,0};
        i32x16 acc1 = {0,0,0,0,0,0,0,0,0,0,0,0,0,0,0,0};
        i32x16 acc2 = {0,0,0,0,0,0,0,0,0,0,0,0,0,0,0,0};
        #pragma unroll
        for (int kp = 0; kp < 8; ++kp) {
            int off = half * 128 + kp * 16;
            i32x4 q = *(const i32x4*)(rbase[nb] + (off ^ ((l31 & 7) << 4)));
            u32x2 p0 = {(unsigned int)q[0], (unsigned int)q[1]};
            u32x2 p1 = {(unsigned int)q[2], (unsigned int)q[3]};
            long a0 = __builtin_bit_cast(long, p0);
            long a1 = __builtin_bit_cast(long, p1);
            acc0 = __builtin_amdgcn_mfma_i32_32x32x16_i8(a0, Bf[0][kp*2],   acc0, 0, 0, 0);
            acc1 = __builtin_amdgcn_mfma_i32_32x32x16_i8(a0, Bf[1][kp*2],   acc1, 0, 0, 0);
            acc2 = __builtin_amdgcn_mfma_i32_32x32x16_i8(a0, Bf[2][kp*2],   acc2, 0, 0, 0);
            acc0 = __builtin_amdgcn_mfma_i32_32x32x16_i8(a1, Bf[0][kp*2+1], acc0, 0, 0, 0);
            acc1 = __builtin_amdgcn_mfma_i32_32x32x16_i8(a1, Bf[1][kp*2+1], acc1, 0, 0, 0);
            acc2 = __builtin_amdgcn_mfma_i32_32x32x16_i8(a1, Bf[2][kp*2+1], acc2, 0, 0, 0);
        }

        int cnt = 0;
        #pragma unroll
        for (int r = 0; r < 16; ++r) {
            int   sv  = (((acc0[r] << 8) + acc1[r]) << 8) + acc2[r];  // exact
            float cv  = fmaf((float)sv, 0x1p-23f, bias[r]);
            float mm  = fmaf(b2, m2[r], cv);
            m2[r] = mm;
            bool s = mm > thr;
            bias[r] = s ? bhm : bh;
            cnt += s ? 1 : 0;
        }
        G = fmaf(b3, G, (float)cnt);
        __syncthreads();
    }

    float acc3 = wo * G;
    #pragma unroll
    for (int off = 32; off; off >>= 1) acc3 += __shfl_xor(acc3, off);
    if (lane == 0) wred[wid] = acc3;
    __syncthreads();
    if (tid == 0) {
        float s = 0.0f;
        #pragma unroll
        for (int wq = 0; wq < 8; ++wq) s += wred[wq];
        partials[blockIdx.x] = s;
    }
}

// ---------------------------------------------------------------------------
// k3: deterministic final reduction + bias/geometric term
// ---------------------------------------------------------------------------
__global__ void k3_final(const float* __restrict__ partials,
                         const float* __restrict__ b_o,
                         const float* __restrict__ beta_o,
                         float* __restrict__ out) {
    __shared__ float wred[4];
    int tid = threadIdx.x, lane = tid & 63, wid = tid >> 6;
    float v = partials[tid];
    #pragma unroll
    for (int off = 32; off; off >>= 1) v += __shfl_xor(v, off);
    if (lane == 0) wred[wid] = v;
    __syncthreads();
    if (tid == 0) {
        float total = (wred[0] + wred[1]) + (wred[2] + wred[3]);
        float b3 = clamp01(beta_o[0]);
        float geo = 0.0f, p = 1.0f;
        #pragma unroll 1
        for (int i = 0; i < 64; ++i) { geo += p; p *= b3; }
        out[0] = total / 8192.0f + b_o[0] * geo;
    }
}

extern "C" void kernel_launch(void* const* d_in, const int* in_sizes, int n_in,
                              void* d_out, int out_size, void* d_ws, size_t ws_size,
                              hipStream_t stream) {
    const float* x       = (const float*)d_in[0];
    const float* W_in    = (const float*)d_in[1];
    const float* b_in    = (const float*)d_in[2];
    const float* beta_in = (const float*)d_in[3];
    const float* thr_in  = (const float*)d_in[4];
    const float* W_h     = (const float*)d_in[5];
    const float* b_h     = (const float*)d_in[6];
    const float* beta_h  = (const float*)d_in[7];
    const float* thr_h   = (const float*)d_in[8];
    const float* W_o     = (const float*)d_in[9];
    const float* b_o     = (const float*)d_in[10];
    const float* beta_o  = (const float*)d_in[11];
    (void)in_sizes; (void)n_in; (void)out_size; (void)ws_size;

    char* ws = (char*)d_ws;
    unsigned long long* S1 = (unsigned long long*)(ws + S1_OFF);
    float*        partials = (float*)(ws + PART_OFF);

    k1_layer1<<<1024, 256, 0, stream>>>(x, W_in, b_in, beta_in, thr_in, S1);
    k2_main  <<<256,  512, 0, stream>>>((const unsigned int*)S1, W_h,
                                        b_h, beta_h, thr_h, W_o, beta_o, partials);
    k3_final <<<1, 256, 0, stream>>>(partials, b_o, beta_o, (float*)d_out);
}

// Round 6
// 344.450 us; speedup vs baseline: 1.0292x; 1.0292x over previous
//
#include <hip/hip_runtime.h>
#include <hip/hip_bf16.h>

typedef float              f32x4 __attribute__((ext_vector_type(4)));
typedef int                i32x4 __attribute__((ext_vector_type(4)));
typedef unsigned int       u32x2 __attribute__((ext_vector_type(2)));
typedef unsigned long long u64x2 __attribute__((ext_vector_type(2)));

// ws layout
#define S1_OFF   0u
#define S1_BYTES (64u * 8192u * 32u)   // 16,777,216 B (bitpacked s1: [t][b][256 bits], bit p = d)
#define PART_OFF S1_BYTES

static __device__ __forceinline__ float clamp01(float v) {
    return fminf(fmaxf(v, 0.0f), 1.0f);
}

// ---------------------------------------------------------------------------
// k1: cur_in = x_t @ W_in^T + b_in (fp32), 64-step layer-1 recurrence,
// s1 bitpacked via __ballot.  8 batches/block, 1024 blocks.
// lane owns h = {lane, +64, +128, +192}; grp = tid>>6 owns batches
// {grp*2, grp*2+1}.  Per t the wave's 8 ballot words (one 64-B region)
// are scattered to lanes 0-3 and stored as two u64 per lane (1 txn vs 8).
// ---------------------------------------------------------------------------
__global__ __launch_bounds__(256) void k1_layer1(
    const float* __restrict__ x, const float* __restrict__ W_in,
    const float* __restrict__ b_in, const float* __restrict__ beta_in,
    const float* __restrict__ thr_in, unsigned long long* __restrict__ S1) {
    __shared__ float Xs[8][256];
    int tid = threadIdx.x;
    int b0 = blockIdx.x * 8;
    #pragma unroll
    for (int i = 0; i < 8; ++i) {
        int idx = i * 256 + tid;
        int bb = idx >> 8, d = idx & 255;
        Xs[bb][d] = x[((size_t)(b0 + bb) * 256 + d) * 64];  // x[0,b,d,0]
    }
    __syncthreads();

    int lane = tid & 63, grp = tid >> 6;
    int   h[4]; float bi[4], b1[4], th[4];
    #pragma unroll
    for (int i = 0; i < 4; ++i) {
        h[i]  = i * 64 + lane;
        bi[i] = b_in[h[i]];
        b1[i] = clamp01(beta_in[h[i]]);
        th[i] = thr_in[h[i]];
    }
    float cur[4][2];
    #pragma unroll
    for (int i = 0; i < 4; ++i)
        #pragma unroll
        for (int bb = 0; bb < 2; ++bb) cur[i][bb] = bi[i];

    #pragma unroll 4
    for (int d4 = 0; d4 < 64; ++d4) {
        f32x4 w[4];
        #pragma unroll
        for (int i = 0; i < 4; ++i)
            w[i] = *(const f32x4*)(W_in + (size_t)h[i] * 256 + d4 * 4);
        #pragma unroll
        for (int bb = 0; bb < 2; ++bb) {
            f32x4 xv = *(const f32x4*)(&Xs[grp * 2 + bb][d4 * 4]);
            #pragma unroll
            for (int i = 0; i < 4; ++i)
                cur[i][bb] += w[i][0]*xv[0] + w[i][1]*xv[1] + w[i][2]*xv[2] + w[i][3]*xv[3];
        }
    }

    float m1[4][2];
    #pragma unroll
    for (int i = 0; i < 4; ++i)
        #pragma unroll
        for (int bb = 0; bb < 2; ++bb) m1[i][bb] = 0.0f;

    int li = lane & 3;
    #pragma unroll 1
    for (int t = 0; t < 64; ++t) {
        unsigned long long arr[8];
        #pragma unroll
        for (int i = 0; i < 4; ++i) {
            #pragma unroll
            for (int bb = 0; bb < 2; ++bb) {
                float mm = m1[i][bb];
                float rst = (mm > th[i]) ? th[i] : 0.0f;   // r1 uses old m1
                mm = b1[i] * mm + cur[i][bb] - rst;
                m1[i][bb] = mm;
                arr[bb * 4 + i] = __ballot(mm > th[i]);    // s1 bits, d = i*64+lane
            }
        }
        // lane li stores arr[2*li], arr[2*li+1] (u64 linear idx = bb*4+i)
        unsigned long long e0 = (li & 2) ? ((li & 1) ? arr[6] : arr[4])
                                         : ((li & 1) ? arr[2] : arr[0]);
        unsigned long long e1 = (li & 2) ? ((li & 1) ? arr[7] : arr[5])
                                         : ((li & 1) ? arr[3] : arr[1]);
        if (lane < 4) {
            unsigned long long* p =
                S1 + ((size_t)t * 8192 + (size_t)(b0 + grp * 2)) * 4 + (size_t)li * 2;
            *(u64x2*)p = (u64x2){e0, e1};
        }
    }
}

// ---------------------------------------------------------------------------
// k2: prologue splits W_h into 3 signed-i8 base-256 digits directly into
// VGPRs (w = a0*2^-7 + a1*2^-15 + a2*2^-23, |err| <= 2^-24; exact int
// extraction), then fused 64-step loop with i8 MFMA, zero LDS in t-loop.
// 256 blocks x 512 thr (8 waves = 2/SIMD).  Block owns 32 batch rows x all
// 256 h cols; wave wid owns cols [wid*32, +32).  Fragment mapping:
//   B[k][col=h]: lane = colL + 16*lsel, byte j; h = nfq*16 + colL,
//   d = lsel*64 + ks*8 + j  (k = ks*32 + lsel*8 + j).
// The 8x-replicated A-unpack VALU is deliberate: it co-schedules with the
// MFMA pipe (m114) and avoids any barrier in the t-loop (r5 regression).
// ---------------------------------------------------------------------------
__global__ __launch_bounds__(512, 2) void k2_main(
    const unsigned int* __restrict__ S1,
    const float* __restrict__ W_h,
    const float* __restrict__ b_h, const float* __restrict__ beta_h,
    const float* __restrict__ thr_h, const float* __restrict__ W_o,
    const float* __restrict__ beta_o, float* __restrict__ partials) {
    __shared__ float wred[8];
    int tid = threadIdx.x, lane = tid & 63, wid = tid >> 6;
    int colL = lane & 15, lsel = lane >> 4;
    int row0 = blockIdx.x * 32;

    // ---- prologue: build persistent B digit-fragments in registers ----
    long Bf[2][3][8];
    #pragma unroll
    for (int nf2 = 0; nf2 < 2; ++nf2) {
        int hrow = (wid * 2 + nf2) * 16 + colL;
        #pragma unroll
        for (int ks = 0; ks < 8; ++ks) {
            const float* wp = W_h + (size_t)hrow * 256 + lsel * 64 + ks * 8;
            unsigned int lo[3] = {0, 0, 0}, hi[3] = {0, 0, 0};
            #pragma unroll
            for (int j = 0; j < 8; ++j) {
                float w = wp[j];
                int v  = (int)rintf(w * 0x1p23f);
                int a2 = ((v + 128) & 255) - 128;  v = (v - a2) >> 8;
                int a1 = ((v + 128) & 255) - 128;  int a0 = (v - a1) >> 8;
                unsigned int sh = (j & 3) * 8;
                unsigned int* dst = (j < 4) ? lo : hi;
                dst[0] |= (unsigned int)(a0 & 255) << sh;
                dst[1] |= (unsigned int)(a1 & 255) << sh;
                dst[2] |= (unsigned int)(a2 & 255) << sh;
            }
            #pragma unroll
            for (int sp = 0; sp < 3; ++sp) {
                u32x2 pk = {lo[sp], hi[sp]};
                Bf[nf2][sp][ks] = __builtin_bit_cast(long, pk);
            }
        }
    }

    float thr[2], b2[2], wo[2], bh[2];
    #pragma unroll
    for (int nf2 = 0; nf2 < 2; ++nf2) {
        int hcol = wid * 32 + nf2 * 16 + colL;
        thr[nf2] = thr_h[hcol];
        b2[nf2]  = clamp01(beta_h[hcol]);
        wo[nf2]  = W_o[hcol];
        bh[nf2]  = b_h[hcol];
    }
    float b3 = clamp01(beta_o[0]);

    float m2[2][2][4], rstv[2][2][4];
    #pragma unroll
    for (int m = 0; m < 2; ++m)
        #pragma unroll
        for (int nf2 = 0; nf2 < 2; ++nf2)
            #pragma unroll
            for (int r = 0; r < 4; ++r) { m2[m][nf2][r] = 0.0f; rstv[m][nf2][r] = 0.0f; }
    float acc3 = 0.0f;

    size_t qoff[2];
    #pragma unroll
    for (int m = 0; m < 2; ++m)
        qoff[m] = (size_t)(row0 + m * 16 + colL) * 8 + (size_t)lsel * 2;  // u32 units

    auto STEP = [&](const u32x2 (&q)[2]) {
        i32x4 acc[3][2][2];
        #pragma unroll
        for (int sp = 0; sp < 3; ++sp)
            #pragma unroll
            for (int m = 0; m < 2; ++m)
                #pragma unroll
                for (int nf2 = 0; nf2 < 2; ++nf2)
                    acc[sp][m][nf2] = (i32x4){0, 0, 0, 0};

        #pragma unroll
        for (int ks = 0; ks < 8; ++ks) {
            long a[2];
            #pragma unroll
            for (int m = 0; m < 2; ++m) {
                unsigned int by = (q[m][ks >> 2] >> ((ks & 3) * 8)) & 0xFFu;
                unsigned int lo = (by & 0xFu) * 0x204081u & 0x01010101u;
                unsigned int hi = (by >> 4)   * 0x204081u & 0x01010101u;
                u32x2 av = {lo, hi};
                a[m] = __builtin_bit_cast(long, av);
            }
            #pragma unroll
            for (int m = 0; m < 2; ++m)
                #pragma unroll
                for (int nf2 = 0; nf2 < 2; ++nf2)
                    #pragma unroll
                    for (int sp = 0; sp < 3; ++sp)
                        acc[sp][m][nf2] = __builtin_amdgcn_mfma_i32_16x16x32_i8(
                            a[m], Bf[nf2][sp][ks], acc[sp][m][nf2], 0, 0, 0);
        }

        float sum = 0.0f;
        #pragma unroll
        for (int m = 0; m < 2; ++m)
            #pragma unroll
            for (int nf2 = 0; nf2 < 2; ++nf2)
                #pragma unroll
                for (int r = 0; r < 4; ++r) {
                    int   s01 = (acc[0][m][nf2][r] << 8) + acc[1][m][nf2][r];  // exact, <2^23
                    float cur = fmaf((float)s01, 0x1p-15f,
                                fmaf((float)acc[2][m][nf2][r], 0x1p-23f, bh[nf2]));
                    float mm = fmaf(b2[nf2], m2[m][nf2][r], cur) - rstv[m][nf2][r];
                    m2[m][nf2][r] = mm;
                    bool s = mm > thr[nf2];
                    rstv[m][nf2][r] = s ? thr[nf2] : 0.0f;
                    sum += s ? wo[nf2] : 0.0f;
                }
        acc3 = fmaf(b3, acc3, sum);
    };

    u32x2 qA[2], qB[2];
    #pragma unroll
    for (int m = 0; m < 2; ++m) qA[m] = *(const u32x2*)(S1 + qoff[m]);

    #pragma unroll 1
    for (int t = 0; t < 64; t += 2) {
        #pragma unroll
        for (int m = 0; m < 2; ++m)
            qB[m] = *(const u32x2*)(S1 + (size_t)(t + 1) * 65536 + qoff[m]);
        STEP(qA);
        if (t + 2 < 64) {
            #pragma unroll
            for (int m = 0; m < 2; ++m)
                qA[m] = *(const u32x2*)(S1 + (size_t)(t + 2) * 65536 + qoff[m]);
        }
        STEP(qB);
    }

    #pragma unroll
    for (int off = 32; off; off >>= 1) acc3 += __shfl_xor(acc3, off);
    if (lane == 0) wred[wid] = acc3;
    __syncthreads();
    if (tid == 0) {
        float s = 0.0f;
        #pragma unroll
        for (int wq = 0; wq < 8; ++wq) s += wred[wq];
        partials[blockIdx.x] = s;
    }
}

// ---------------------------------------------------------------------------
// k3: deterministic final reduction + bias/geometric term
// ---------------------------------------------------------------------------
__global__ void k3_final(const float* __restrict__ partials,
                         const float* __restrict__ b_o,
                         const float* __restrict__ beta_o,
                         float* __restrict__ out) {
    __shared__ float wred[4];
    int tid = threadIdx.x, lane = tid & 63, wid = tid >> 6;
    float v = partials[tid];
    #pragma unroll
    for (int off = 32; off; off >>= 1) v += __shfl_xor(v, off);
    if (lane == 0) wred[wid] = v;
    __syncthreads();
    if (tid == 0) {
        float total = (wred[0] + wred[1]) + (wred[2] + wred[3]);
        float b3 = clamp01(beta_o[0]);
        float geo = 0.0f, p = 1.0f;
        #pragma unroll 1
        for (int i = 0; i < 64; ++i) { geo += p; p *= b3; }
        out[0] = total / 8192.0f + b_o[0] * geo;
    }
}

extern "C" void kernel_launch(void* const* d_in, const int* in_sizes, int n_in,
                              void* d_out, int out_size, void* d_ws, size_t ws_size,
                              hipStream_t stream) {
    const float* x       = (const float*)d_in[0];
    const float* W_in    = (const float*)d_in[1];
    const float* b_in    = (const float*)d_in[2];
    const float* beta_in = (const float*)d_in[3];
    const float* thr_in  = (const float*)d_in[4];
    const float* W_h     = (const float*)d_in[5];
    const float* b_h     = (const float*)d_in[6];
    const float* beta_h  = (const float*)d_in[7];
    const float* thr_h   = (const float*)d_in[8];
    const float* W_o     = (const float*)d_in[9];
    const float* b_o     = (const float*)d_in[10];
    const float* beta_o  = (const float*)d_in[11];
    (void)in_sizes; (void)n_in; (void)out_size; (void)ws_size;

    char* ws = (char*)d_ws;
    unsigned long long* S1 = (unsigned long long*)(ws + S1_OFF);
    float*        partials = (float*)(ws + PART_OFF);

    k1_layer1<<<1024, 256, 0, stream>>>(x, W_in, b_in, beta_in, thr_in, S1);
    k2_main  <<<256,  512, 0, stream>>>((const unsigned int*)S1, W_h,
                                        b_h, beta_h, thr_h, W_o, beta_o, partials);
    k3_final <<<1, 256, 0, stream>>>(partials, b_o, beta_o, (float*)d_out);
}